// Round 4
// baseline (11371.856 us; speedup 1.0000x reference)
//
#include <hip/hip_runtime.h>
#include <hip/hip_bf16.h>
#include <hip/hip_cooperative_groups.h>
#include <cstdint>

namespace cg = cooperative_groups;

#define T_STEPS 100
#define BATCH 256
#define NIN 700
#define H1 2048
#define H2 2048
#define NOUT 20

typedef __attribute__((ext_vector_type(8))) short bf16x8;
typedef __attribute__((ext_vector_type(4))) float f32x4;
typedef unsigned long long ull;

__device__ __forceinline__ unsigned short f2bf(float x) {
    __hip_bfloat16 h = __float2bfloat16(x);
    return *(unsigned short*)&h;
}
__device__ __forceinline__ float bf2f(unsigned short u) {
    __hip_bfloat16 h = *(__hip_bfloat16*)&u;
    return __bfloat162float(h);
}

// ---------------- split W2|V into bf16 hi/mid/lo, layout [term][j][4096k] ----
__global__ __launch_bounds__(256) void split_kernel(
    const float* __restrict__ W2, const float* __restrict__ V,
    unsigned short* __restrict__ Bsplit)
{
    const size_t D = (size_t)2048 * 4096;
    size_t i = (size_t)blockIdx.x * 256 + threadIdx.x;
    int j = (int)(i >> 12), k = (int)(i & 4095);
    float w = (k < 2048) ? W2[(size_t)j * 2048 + k] : V[(size_t)j * 2048 + (k - 2048)];
    unsigned short h = f2bf(w);
    float r1 = w - bf2f(h);
    unsigned short m = f2bf(r1);
    float r2 = r1 - bf2f(m);
    unsigned short l = f2bf(r2);
    Bsplit[i] = h;
    Bsplit[D + i] = m;
    Bsplit[2 * D + i] = l;
}

// ---------------- layer 1: fused GEMM (x@W1.T) + leaky scan + bitpack ----
__global__ __launch_bounds__(256) void l1_kernel(
    const float* __restrict__ data, const float* __restrict__ W1,
    const float* __restrict__ b1,
    const float* __restrict__ p_beta1, const float* __restrict__ p_thr1,
    ull* __restrict__ s1bits)
{
    __shared__ float lds[7168];
    float* A  = lds;                     // [28][112]
    float* Wl = lds + 3136;              // [28][65]
    const int jt = blockIdx.x, b = blockIdx.y;
    const int j0 = jt * 64;
    const int j = threadIdx.x & 63, g = threadIdx.x >> 6;
    float acc[28];
    #pragma unroll
    for (int i = 0; i < 28; ++i) acc[i] = 0.f;
    const float* db = data + (size_t)b * (NIN * T_STEPS);

    for (int k0 = 0; k0 < NIN; k0 += 28) {
        for (int idx = threadIdx.x; idx < 784; idx += 256) {
            int kk = idx / 28, q = idx - kk * 28;
            float4 v;
            if (q < 25) v = *(const float4*)(db + (size_t)(k0 + kk) * T_STEPS + q * 4);
            else { v.x = 0.f; v.y = 0.f; v.z = 0.f; v.w = 0.f; }
            *(float4*)(A + kk * 112 + q * 4) = v;
        }
        for (int idx = threadIdx.x; idx < 1792; idx += 256) {
            int j2 = idx / 28, kk = idx - j2 * 28;
            Wl[kk * 65 + j2] = W1[(size_t)(j0 + j2) * NIN + k0 + kk];
        }
        __syncthreads();
        #pragma unroll 4
        for (int kk = 0; kk < 28; ++kk) {
            float wv = Wl[kk * 65 + j];
            const float4* av = (const float4*)(A + kk * 112 + g * 28);
            #pragma unroll
            for (int q = 0; q < 7; ++q) {
                float4 a4 = av[q];
                acc[q*4+0] = fmaf(a4.x, wv, acc[q*4+0]);
                acc[q*4+1] = fmaf(a4.y, wv, acc[q*4+1]);
                acc[q*4+2] = fmaf(a4.z, wv, acc[q*4+2]);
                acc[q*4+3] = fmaf(a4.w, wv, acc[q*4+3]);
            }
        }
        __syncthreads();
    }
    #pragma unroll
    for (int tt = 0; tt < 28; ++tt)
        lds[(g * 28 + tt) * 64 + j] = acc[tt];
    __syncthreads();
    if (threadIdx.x < 64) {
        const float beta1 = *p_beta1, thr1 = *p_thr1;
        const float b1j = b1[j0 + j];
        float m = 0.f;
        for (int t = 0; t < T_STEPS; ++t) {
            m = fmaf(beta1, m, lds[t * 64 + j]) + b1j;
            bool pred = (m - thr1) > 0.f;
            ull mask = __ballot(pred);
            if (pred) m -= thr1;
            if (j == 0) s1bits[((size_t)t * BATCH + b) * 32 + jt] = mask;
        }
    }
}

// ---------------- persistent cooperative chain: all 100 steps, one launch ----
__global__ __launch_bounds__(256, 1) void chain_kernel(
    const ull* __restrict__ s1bits,
    unsigned short* __restrict__ srbA,   // pre-zeroed: holds s_r(-1)
    unsigned short* __restrict__ srbB,
    const unsigned short* __restrict__ Bsplit,
    const float* __restrict__ b2,
    const float* __restrict__ W3, const float* __restrict__ b3,
    float* __restrict__ out,
    const float* p_beta_r, const float* p_thr_r,
    const float* p_back_beta, const float* p_alpha,
    const float* p_beta2, const float* p_thr2)
{
    cg::grid_group grid = cg::this_grid();
    __shared__ float Cred[4][128][16];          // 32 KB cross-wave reduction
    __shared__ float s3[2048];                  // l3 spike floats
    __shared__ ull w3stage[32];
    __shared__ unsigned char mbytes[256];
    __shared__ float redl3[4][NOUT];
    __shared__ float mem2L[NOUT];

    const int tid = threadIdx.x;
    const int lane = tid & 63, wv = tid >> 6;
    const int q = lane >> 4, n16 = lane & 15;
    const int jt = blockIdx.x & 127, bt = blockIdx.x >> 7;
    const int j0 = jt << 4, b0 = bt << 7;
    const int b_own = blockIdx.x;
    const float beta_r = *p_beta_r, thr_r = *p_thr_r;
    const float back_beta = *p_back_beta, alpha = *p_alpha;
    const float beta2 = *p_beta2, thr2 = *p_thr2;

    // neuron-state cells: thread covers b_local=tid>>1, j_local=(tid&1)*8+e
    const int bl_cell = tid >> 1, jb = (tid & 1) << 3;
    float memr[8], ahpr[8], b2r[8];
    #pragma unroll
    for (int e = 0; e < 8; ++e) { memr[e] = 0.f; ahpr[e] = 0.f; b2r[e] = b2[j0 + jb + e]; }
    if (tid < NOUT) mem2L[tid] = 0.f;
    __syncthreads();

    auto l3_compute = [&](const unsigned short* buf, int tt) {
        if (tid < 32)
            w3stage[tid] = __hip_atomic_load((ull*)buf + (size_t)b_own * 32 + tid,
                                             __ATOMIC_RELAXED, __HIP_MEMORY_SCOPE_AGENT);
        __syncthreads();
        ull wd = w3stage[tid >> 3];
        unsigned int byv = (unsigned int)(wd >> ((tid & 7) << 3)) & 0xFFu;
        #pragma unroll
        for (int e = 0; e < 8; ++e) s3[tid * 8 + e] = ((byv >> e) & 1u) ? 1.f : 0.f;
        __syncthreads();
        float s8[8];
        #pragma unroll
        for (int e = 0; e < 8; ++e) s8[e] = s3[tid * 8 + e];
        #pragma unroll
        for (int o = 0; o < NOUT; ++o) {
            const float4* wp = (const float4*)(W3 + (size_t)o * 2048 + tid * 8);
            float4 wa = wp[0], wb = wp[1];
            float v = s8[0]*wa.x + s8[1]*wa.y + s8[2]*wa.z + s8[3]*wa.w
                    + s8[4]*wb.x + s8[5]*wb.y + s8[6]*wb.z + s8[7]*wb.w;
            #pragma unroll
            for (int msk = 32; msk > 0; msk >>= 1)
                v += __shfl_xor(v, msk, 64);
            if (lane == 0) redl3[wv][o] = v;
        }
        __syncthreads();
        if (tid < NOUT) {
            float cur = redl3[0][tid] + redl3[1][tid] + redl3[2][tid] + redl3[3][tid] + b3[tid];
            float m = fmaf(beta2, mem2L[tid], cur);
            bool pred = (m - thr2) > 0.f;
            if (pred) m -= thr2;
            mem2L[tid] = m;
            out[(size_t)tt * (BATCH * NOUT) + b_own * NOUT + tid] = pred ? 1.f : 0.f;
        }
        __syncthreads();
    };

    for (int t = 0; t < T_STEPS; ++t) {
        const unsigned short* prevbuf = (t & 1) ? srbB : srbA;  // s_r(t-1)
        unsigned short* curbuf = (t & 1) ? srbA : srbB;         // s_r(t)
        if (t > 0) l3_compute(prevbuf, t - 1);

        const ull* s1t = s1bits + (size_t)t * BATCH * 32;
        f32x4 acc[8] = {};
        for (int c = 0; c < 16; ++c) {
            const int w64 = (wv << 4) + c;        // K-window of 64 k's
            ull wrd[8];
            #pragma unroll
            for (int i = 0; i < 8; ++i) {
                int row = b0 + (i << 4) + n16;
                if (w64 < 32) wrd[i] = s1t[(size_t)row * 32 + w64];
                else wrd[i] = __hip_atomic_load((ull*)prevbuf + (size_t)row * 32 + (w64 - 32),
                                                __ATOMIC_RELAXED, __HIP_MEMORY_SCOPE_AGENT);
            }
            const int kin = w64 << 6;
            #pragma unroll
            for (int kk = 0; kk < 2; ++kk) {
                bf16x8 af[8];
                const int bsel = (kk << 2) + q;   // byte of the 64-bit word
                #pragma unroll
                for (int i = 0; i < 8; ++i) {
                    unsigned int byv = (unsigned int)(wrd[i] >> (bsel << 3)) & 0xFFu;
                    union { unsigned int u[4]; bf16x8 v; } U;
                    #pragma unroll
                    for (int p = 0; p < 4; ++p)
                        U.u[p] = (((byv >> (2*p)) & 1u) ? 0x3F80u : 0u)
                               | (((byv >> (2*p+1)) & 1u) ? 0x3F800000u : 0u);
                    af[i] = U.v;
                }
                #pragma unroll
                for (int term = 0; term < 3; ++term) {
                    const unsigned short* bp = Bsplit + ((size_t)term << 23)
                        + (size_t)(j0 + n16) * 4096 + kin + (kk << 5) + (q << 3);
                    bf16x8 bfr = *(const bf16x8*)bp;
                    #pragma unroll
                    for (int i = 0; i < 8; ++i)
                        acc[i] = __builtin_amdgcn_mfma_f32_16x16x32_bf16(af[i], bfr, acc[i], 0, 0, 0);
                }
            }
        }
        // cross-wave K reduction (deterministic order)
        #pragma unroll
        for (int i = 0; i < 8; ++i)
            #pragma unroll
            for (int r = 0; r < 4; ++r)
                Cred[wv][(i << 4) + (q << 2) + r][n16] = acc[i][r];
        __syncthreads();
        unsigned int mask8 = 0;
        #pragma unroll
        for (int e = 0; e < 8; ++e) {
            int jl = jb + e;
            float cv = Cred[0][bl_cell][jl] + Cred[1][bl_cell][jl]
                     + Cred[2][bl_cell][jl] + Cred[3][bl_cell][jl];
            float m = fmaf(beta_r, memr[e], cv + b2r[e]) - ahpr[e];
            bool pred = (m - thr_r) > 0.f;
            float s = pred ? 1.f : 0.f;
            if (pred) m -= thr_r;
            ahpr[e] = fmaf(back_beta, ahpr[e], alpha * s);
            memr[e] = m;
            mask8 |= (pred ? 1u : 0u) << e;
        }
        mbytes[tid] = (unsigned char)mask8;
        __syncthreads();
        if (tid < 128) {
            unsigned short hw = (unsigned short)(mbytes[2*tid] | (mbytes[2*tid+1] << 8));
            __hip_atomic_store(&curbuf[(size_t)(b0 + tid) * 128 + jt], hw,
                               __ATOMIC_RELAXED, __HIP_MEMORY_SCOPE_AGENT);
        }
        __threadfence();
        grid.sync();
    }
    // final layer-3: s_r(99) lives in srbA (t=99 odd wrote srbA)
    l3_compute(srbA, T_STEPS - 1);
}

extern "C" void kernel_launch(void* const* d_in, const int* in_sizes, int n_in,
                              void* d_out, int out_size, void* d_ws, size_t ws_size,
                              hipStream_t stream)
{
    const float* data   = (const float*)d_in[0];
    const float* W1     = (const float*)d_in[1];
    const float* b1     = (const float*)d_in[2];
    const float* W2     = (const float*)d_in[3];
    const float* b2     = (const float*)d_in[4];
    const float* V      = (const float*)d_in[5];
    const float* W3     = (const float*)d_in[6];
    const float* b3     = (const float*)d_in[7];
    const float* beta1  = (const float*)d_in[8];
    const float* thr1   = (const float*)d_in[9];
    const float* beta_r = (const float*)d_in[10];
    const float* thr_r  = (const float*)d_in[11];
    const float* back_beta = (const float*)d_in[12];
    const float* alpha  = (const float*)d_in[13];
    const float* beta2  = (const float*)d_in[14];
    const float* thr2   = (const float*)d_in[15];
    float* out = (float*)d_out;
    (void)in_sizes; (void)n_in; (void)out_size; (void)ws_size;

    char* p = (char*)d_ws;
    auto carve = [&](size_t bytes) {
        char* r = p; p += (bytes + 255) & ~(size_t)255; return r;
    };
    ull* s1bits = (ull*)carve((size_t)T_STEPS*BATCH*32*8);                   // 6.55 MB
    unsigned short* srbA = (unsigned short*)carve((size_t)BATCH*128*2);      // 64 KB
    unsigned short* srbB = (unsigned short*)carve((size_t)BATCH*128*2);      // 64 KB
    unsigned short* Bsplit = (unsigned short*)carve((size_t)3*2048*4096*2);  // 50.3 MB

    hipMemsetAsync(srbA, 0, (size_t)BATCH*128*2, stream);

    split_kernel<<<(2048*4096)/256, 256, 0, stream>>>(W2, V, Bsplit);
    l1_kernel<<<dim3(32,256), 256, 0, stream>>>(data, W1, b1, beta1, thr1, s1bits);

    void* args[] = {
        (void*)&s1bits, (void*)&srbA, (void*)&srbB, (void*)&Bsplit,
        (void*)&b2, (void*)&W3, (void*)&b3, (void*)&out,
        (void*)&beta_r, (void*)&thr_r, (void*)&back_beta, (void*)&alpha,
        (void*)&beta2, (void*)&thr2
    };
    hipLaunchCooperativeKernel((void*)chain_kernel, dim3(256), dim3(256),
                               args, 0, stream);
}

// Round 5
// 4764.962 us; speedup vs baseline: 2.3866x; 2.3866x over previous
//
#include <hip/hip_runtime.h>
#include <hip/hip_bf16.h>
#include <cstdint>

#define T_STEPS 100
#define BATCH 256
#define NIN 700
#define H1 2048
#define H2 2048
#define NOUT 20
#define KS 16           // K-split factor for l2 GEMM
#define KCH 12          // 64-wide K chunks per block: 12288/(KS*64)

typedef __attribute__((ext_vector_type(8))) short bf16x8;
typedef __attribute__((ext_vector_type(4))) float f32x4;
typedef unsigned long long ull;

__device__ __forceinline__ void async16(void* lds, const void* g) {
    __builtin_amdgcn_global_load_lds(
        (const __attribute__((address_space(1))) unsigned int*)g,
        (__attribute__((address_space(3))) unsigned int*)lds, 16, 0, 0);
}

__device__ __forceinline__ unsigned short f2bf(float x) {
    __hip_bfloat16 h = __float2bfloat16(x);
    return *(unsigned short*)&h;
}
__device__ __forceinline__ float bf2f(unsigned short u) {
    __hip_bfloat16 h = *(__hip_bfloat16*)&u;
    return __bfloat162float(h);
}

// ---------------- split W2|V into bf16 hi/mid/lo, layout [term][j][4096k] ----
__global__ __launch_bounds__(256) void split_kernel(
    const float* __restrict__ W2, const float* __restrict__ V,
    unsigned short* __restrict__ Bsplit)
{
    const size_t D = (size_t)2048 * 4096;
    size_t i = (size_t)blockIdx.x * 256 + threadIdx.x;
    int j = (int)(i >> 12), k = (int)(i & 4095);
    float w = (k < 2048) ? W2[(size_t)j * 2048 + k] : V[(size_t)j * 2048 + (k - 2048)];
    unsigned short h = f2bf(w);
    float r1 = w - bf2f(h);
    unsigned short m = f2bf(r1);
    float r2 = r1 - bf2f(m);
    unsigned short l = f2bf(r2);
    Bsplit[i] = h;
    Bsplit[D + i] = m;
    Bsplit[2 * D + i] = l;
}

// ---------------- split W1 into granule-major bf16 planes ------------------
// W1f[term][g 0..87][j 0..2047][8] ; k = g*8+e, zero-padded k>=700.
__global__ __launch_bounds__(256) void w1split_kernel(
    const float* __restrict__ W1, unsigned short* __restrict__ W1f)
{
    const size_t P = (size_t)88 * 2048 * 8;   // elems per term
    int id = blockIdx.x * 256 + threadIdx.x;  // 0..180223
    int g = id >> 11, j = id & 2047;
    unsigned short h8[8], m8[8], l8[8];
    #pragma unroll
    for (int e = 0; e < 8; ++e) {
        int k = g * 8 + e;
        float v = (k < NIN) ? W1[(size_t)j * NIN + k] : 0.f;
        unsigned short h = f2bf(v); float r1 = v - bf2f(h);
        unsigned short m = f2bf(r1); float r2 = r1 - bf2f(m);
        h8[e] = h; m8[e] = m; l8[e] = f2bf(r2);
    }
    size_t base = (((size_t)g * 2048) + j) * 8;
    *(uint4*)(W1f + base)         = *(uint4*)h8;
    *(uint4*)(W1f + P + base)     = *(uint4*)m8;
    *(uint4*)(W1f + 2 * P + base) = *(uint4*)l8;
}

// ---------------- layer 1 via MFMA: x@W1.T (6-term bf16) + scan + bitpack ----
// grid 2048 = 8 jt (bid&7, XCD-locality) x 256 b. Block 256 thr / 4 waves.
// Wave w: j = jt*256 + w*64 .. +63, all 7 m-tiles (t=0..111 pad).
__global__ __launch_bounds__(256) void l1m_kernel(
    const float* __restrict__ data, const unsigned short* __restrict__ W1f,
    const float* __restrict__ b1,
    const float* __restrict__ p_beta1, const float* __restrict__ p_thr1,
    ull* __restrict__ s1bits)
{
    __shared__ __align__(16) char smem[33280];  // union: Af 21.5KB | Cw 4x8.3KB
    unsigned short* Af = (unsigned short*)smem; // [3 term][4 g][112 t][8]
    const int tid = threadIdx.x, lane = tid & 63, w = tid >> 6;
    const int n16 = lane & 15, q = lane >> 4;
    const int jt = blockIdx.x & 7, b = blockIdx.x >> 3;
    const int j0w = jt * 256 + w * 64;
    const float* xb = data + (size_t)b * (NIN * T_STEPS);
    const size_t P = (size_t)88 * 2048 * 8;

    f32x4 acc[7][4] = {};
    for (int c = 0; c < 22; ++c) {
        const int kbase = c * 32;
        // stage + convert A: item = (granule g, t); lanes sweep t (coalesced)
        for (int it = tid; it < 448; it += 256) {
            int g = it / 112, t = it - g * 112;
            unsigned short h8[8], m8[8], l8[8];
            #pragma unroll
            for (int e = 0; e < 8; ++e) {
                int k = kbase + g * 8 + e;
                float v = (t < T_STEPS && k < NIN) ? xb[(size_t)k * T_STEPS + t] : 0.f;
                unsigned short h = f2bf(v); float r1 = v - bf2f(h);
                unsigned short m = f2bf(r1); float r2 = r1 - bf2f(m);
                h8[e] = h; m8[e] = m; l8[e] = f2bf(r2);
            }
            unsigned short* dst = Af + g * 896 + t * 8;
            *(uint4*)(dst)        = *(uint4*)h8;
            *(uint4*)(dst + 3584) = *(uint4*)m8;
            *(uint4*)(dst + 7168) = *(uint4*)l8;
        }
        __syncthreads();
        // B fragments: direct global->reg, 16B/lane coalesced over n16
        bf16x8 bh[4], bm[4], bl[4];
        const size_t gq = (size_t)(c * 4 + q);
        #pragma unroll
        for (int n = 0; n < 4; ++n) {
            size_t off = (gq * 2048 + (size_t)(j0w + n * 16 + n16)) * 8;
            bh[n] = *(const bf16x8*)(W1f + off);
            bm[n] = *(const bf16x8*)(W1f + P + off);
            bl[n] = *(const bf16x8*)(W1f + 2 * P + off);
        }
        #pragma unroll
        for (int m = 0; m < 7; ++m) {
            const unsigned short* ap = Af + q * 896 + (m * 16 + n16) * 8;
            bf16x8 ah = *(const bf16x8*)(ap);
            bf16x8 am = *(const bf16x8*)(ap + 3584);
            bf16x8 al = *(const bf16x8*)(ap + 7168);
            #pragma unroll
            for (int n = 0; n < 4; ++n) {
                acc[m][n] = __builtin_amdgcn_mfma_f32_16x16x32_bf16(ah, bh[n], acc[m][n], 0, 0, 0);
                acc[m][n] = __builtin_amdgcn_mfma_f32_16x16x32_bf16(ah, bm[n], acc[m][n], 0, 0, 0);
                acc[m][n] = __builtin_amdgcn_mfma_f32_16x16x32_bf16(am, bh[n], acc[m][n], 0, 0, 0);
                acc[m][n] = __builtin_amdgcn_mfma_f32_16x16x32_bf16(ah, bl[n], acc[m][n], 0, 0, 0);
                acc[m][n] = __builtin_amdgcn_mfma_f32_16x16x32_bf16(al, bh[n], acc[m][n], 0, 0, 0);
                acc[m][n] = __builtin_amdgcn_mfma_f32_16x16x32_bf16(am, bm[n], acc[m][n], 0, 0, 0);
            }
        }
        __syncthreads();
    }
    // epilogue: per-wave transpose (32 t at a time) + leaky scan + bitpack
    float* Cw = (float*)smem + w * (32 * 65);
    const float beta1 = *p_beta1, thr1 = *p_thr1;
    const float b1j = b1[j0w + lane];
    float mem = 0.f;
    for (int s = 0; s < 4; ++s) {
        #pragma unroll
        for (int mm = 0; mm < 2; ++mm) {
            int m = s * 2 + mm;
            if (m < 7) {
                #pragma unroll
                for (int n = 0; n < 4; ++n)
                    #pragma unroll
                    for (int r = 0; r < 4; ++r)
                        Cw[(mm * 16 + q * 4 + r) * 65 + n * 16 + n16] = acc[m][n][r];
            }
        }
        int tcnt = (s < 3) ? 32 : 4;
        for (int tt = 0; tt < tcnt; ++tt) {
            float v = Cw[tt * 65 + lane];
            mem = fmaf(beta1, mem, v) + b1j;
            bool pred = (mem - thr1) > 0.f;
            ull mask = __ballot(pred);
            if (pred) mem -= thr1;
            if (lane == 0) {
                int tg = s * 32 + tt;
                s1bits[((size_t)tg * BATCH + b) * 32 + jt * 4 + w] = mask;
            }
        }
    }
}

// ---------------- l2 GEMM (per step): Cpart[ks][256b][2048j] partials --------
__global__ __launch_bounds__(256, 2) void l2gemm_kernel(
    const ull* __restrict__ s1bits_t,
    const ull* __restrict__ srb_in,
    const unsigned short* __restrict__ Bsplit,
    float* __restrict__ Cpart)
{
    __shared__ __align__(16) unsigned short Alds[256 * 64];
    __shared__ __align__(16) unsigned short Blds[64 * 64];
    const int bid = blockIdx.x;
    const int nt = bid & 31, ks = bid >> 5;
    const int n0 = nt << 6;
    const int t = threadIdx.x;
    const int lane = t & 63, w = t >> 6;
    f32x4 acc[4][4] = {};

    const int fbase = ks * (12288 / KS);
    for (int c = 0; c < KCH; ++c) {
        const int f = fbase + (c << 6);
        const int term = f >> 12;
        const int kin = f & 4095;
        const unsigned short* Bg = Bsplit + ((size_t)term << 23);
        #pragma unroll
        for (int i = 0; i < 2; ++i) {
            int d = (w << 7) + (i << 6) + lane;
            int row = d >> 3, g8 = d & 7;
            int k16s = g8 ^ (row & 7);
            const unsigned short* g = Bg + (size_t)(n0 + row) * 4096 + kin + (k16s << 3);
            async16(Blds + (((w << 7) + (i << 6)) << 3), (const void*)g);
        }
        {
            ull word = (kin < 2048)
                ? s1bits_t[((size_t)t << 5) + (kin >> 6)]
                : srb_in[((size_t)t << 5) + ((kin - 2048) >> 6)];
            #pragma unroll
            for (int g8 = 0; g8 < 8; ++g8) {
                unsigned int u[4];
                #pragma unroll
                for (int p = 0; p < 4; ++p) {
                    int bit = (g8 << 3) + (p << 1);
                    u[p] = (((word >> bit) & 1ull) ? 0x3F80u : 0u)
                         | (((word >> (bit + 1)) & 1ull) ? 0x3F800000u : 0u);
                }
                int gdst = (t << 3) + (g8 ^ (t & 7));
                *(uint4*)(Alds + (gdst << 3)) = *(uint4*)u;
            }
        }
        __syncthreads();
        #pragma unroll
        for (int kk = 0; kk < 2; ++kk) {
            bf16x8 af[4], bfr[4];
            const int q = lane >> 4, k16 = (kk << 2) + q;
            #pragma unroll
            for (int i = 0; i < 4; ++i) {
                int ra = (w << 6) + (i << 4) + (lane & 15);
                af[i] = *(const bf16x8*)(Alds + (((ra << 3) + (k16 ^ (ra & 7))) << 3));
            }
            #pragma unroll
            for (int j = 0; j < 4; ++j) {
                int rb = (j << 4) + (lane & 15);
                bfr[j] = *(const bf16x8*)(Blds + (((rb << 3) + (k16 ^ (rb & 7))) << 3));
            }
            #pragma unroll
            for (int i = 0; i < 4; ++i)
                #pragma unroll
                for (int j = 0; j < 4; ++j)
                    acc[i][j] = __builtin_amdgcn_mfma_f32_16x16x32_bf16(af[i], bfr[j], acc[i][j], 0, 0, 0);
        }
        __syncthreads();
    }
    float* Cp = Cpart + ((size_t)ks << 19);
    #pragma unroll
    for (int i = 0; i < 4; ++i) {
        int rg = (w << 6) + (i << 4) + ((lane >> 4) << 2);
        #pragma unroll
        for (int j = 0; j < 4; ++j) {
            int cg = n0 + (j << 4) + (lane & 15);
            #pragma unroll
            for (int r = 0; r < 4; ++r)
                Cp[(size_t)(rg + r) * 2048 + cg] = acc[i][j][r];
        }
    }
}

// ---------------- finish (per step): sum partials, AHP neuron, bits, layer3 --
__global__ __launch_bounds__(256) void l2fin_kernel(
    const float* __restrict__ Cpart, const float* __restrict__ b2,
    float* __restrict__ mem_r, float* __restrict__ ahp,
    ull* __restrict__ srb_out,
    const float* __restrict__ W3, const float* __restrict__ b3,
    float* __restrict__ mem2, float* __restrict__ out_t,
    const float* __restrict__ p_beta_r, const float* __restrict__ p_thr_r,
    const float* __restrict__ p_back_beta, const float* __restrict__ p_alpha,
    const float* __restrict__ p_beta2, const float* __restrict__ p_thr2)
{
    __shared__ float sLDS[2048];
    __shared__ float red[4][NOUT];
    const int b = blockIdx.x, t = threadIdx.x;
    const int lane = t & 63, wv = t >> 6;
    const float beta_r = *p_beta_r, thr_r = *p_thr_r;
    const float bb = *p_back_beta, al = *p_alpha;
    #pragma unroll
    for (int u = 0; u < 8; ++u) {
        int j = t + (u << 8);
        size_t cidx = (size_t)b * 2048 + j;
        float x = 0.f;
        #pragma unroll
        for (int p = 0; p < KS; ++p) x += Cpart[((size_t)p << 19) + cidx];
        float cur = x + b2[j];
        float m = fmaf(beta_r, mem_r[cidx], cur) - ahp[cidx];
        bool pred = (m - thr_r) > 0.f;
        ull mask = __ballot(pred);
        float s = pred ? 1.f : 0.f;
        if (pred) m -= thr_r;
        mem_r[cidx] = m;
        ahp[cidx] = fmaf(bb, ahp[cidx], al * s);
        sLDS[j] = s;
        if (lane == 0) srb_out[((size_t)b << 5) + (u << 2) + wv] = mask;
    }
    __syncthreads();
    float s8[8];
    #pragma unroll
    for (int i = 0; i < 8; ++i) s8[i] = sLDS[t * 8 + i];
    float po[NOUT];
    #pragma unroll
    for (int o = 0; o < NOUT; ++o) {
        const float4* wp = (const float4*)(W3 + (size_t)o * 2048 + t * 8);
        float4 wa = wp[0], wb2 = wp[1];
        float v = s8[0]*wa.x + s8[1]*wa.y + s8[2]*wa.z + s8[3]*wa.w
                + s8[4]*wb2.x + s8[5]*wb2.y + s8[6]*wb2.z + s8[7]*wb2.w;
        #pragma unroll
        for (int msk = 32; msk > 0; msk >>= 1)
            v += __shfl_xor(v, msk, 64);
        po[o] = v;
    }
    if (lane == 0) {
        #pragma unroll
        for (int o = 0; o < NOUT; ++o) red[wv][o] = po[o];
    }
    __syncthreads();
    if (t < NOUT) {
        const float beta2 = *p_beta2, thr2 = *p_thr2;
        float cur = red[0][t] + red[1][t] + red[2][t] + red[3][t] + b3[t];
        float m = fmaf(beta2, mem2[b * NOUT + t], cur);
        bool pred = (m - thr2) > 0.f;
        float s2 = pred ? 1.f : 0.f;
        if (pred) m -= thr2;
        mem2[b * NOUT + t] = m;
        out_t[b * NOUT + t] = s2;
    }
}

extern "C" void kernel_launch(void* const* d_in, const int* in_sizes, int n_in,
                              void* d_out, int out_size, void* d_ws, size_t ws_size,
                              hipStream_t stream)
{
    const float* data   = (const float*)d_in[0];
    const float* W1     = (const float*)d_in[1];
    const float* b1     = (const float*)d_in[2];
    const float* W2     = (const float*)d_in[3];
    const float* b2     = (const float*)d_in[4];
    const float* V      = (const float*)d_in[5];
    const float* W3     = (const float*)d_in[6];
    const float* b3     = (const float*)d_in[7];
    const float* beta1  = (const float*)d_in[8];
    const float* thr1   = (const float*)d_in[9];
    const float* beta_r = (const float*)d_in[10];
    const float* thr_r  = (const float*)d_in[11];
    const float* back_beta = (const float*)d_in[12];
    const float* alpha  = (const float*)d_in[13];
    const float* beta2  = (const float*)d_in[14];
    const float* thr2   = (const float*)d_in[15];
    float* out = (float*)d_out;
    (void)in_sizes; (void)n_in; (void)out_size; (void)ws_size;

    char* p = (char*)d_ws;
    auto carve = [&](size_t bytes) {
        char* r = p; p += (bytes + 255) & ~(size_t)255; return r;
    };
    ull* s1bits = (ull*)carve((size_t)T_STEPS*BATCH*32*8);                   // 6.55 MB
    ull* srb0   = (ull*)carve((size_t)BATCH*32*8);
    ull* srb1   = (ull*)carve((size_t)BATCH*32*8);
    float* mem_r = (float*)carve((size_t)BATCH*H2*4);
    float* ahp   = (float*)carve((size_t)BATCH*H2*4);
    float* mem2  = (float*)carve((size_t)BATCH*NOUT*4);
    unsigned short* Bsplit = (unsigned short*)carve((size_t)3*2048*4096*2);  // 50.3 MB
    float* Cpart = (float*)carve((size_t)KS*BATCH*H2*4);                     // 33.6 MB
    unsigned short* W1f = (unsigned short*)carve((size_t)3*88*2048*8*2);     // 8.65 MB

    hipMemsetAsync(srb0, 0, (size_t)BATCH*32*8, stream);
    hipMemsetAsync(mem_r, 0, (size_t)BATCH*H2*4, stream);
    hipMemsetAsync(ahp,  0, (size_t)BATCH*H2*4, stream);
    hipMemsetAsync(mem2, 0, (size_t)BATCH*NOUT*4, stream);

    split_kernel<<<(2048*4096)/256, 256, 0, stream>>>(W2, V, Bsplit);
    w1split_kernel<<<704, 256, 0, stream>>>(W1, W1f);
    l1m_kernel<<<2048, 256, 0, stream>>>(data, W1f, b1, beta1, thr1, s1bits);

    ull* srb[2] = {srb0, srb1};
    for (int t = 0; t < T_STEPS; ++t) {
        const ull* sin = srb[t & 1];
        ull* sout = srb[(t + 1) & 1];
        l2gemm_kernel<<<512, 256, 0, stream>>>(s1bits + (size_t)t*BATCH*32, sin,
                                               Bsplit, Cpart);
        l2fin_kernel<<<256, 256, 0, stream>>>(Cpart, b2, mem_r, ahp, sout,
                                              W3, b3, mem2, out + (size_t)t*BATCH*NOUT,
                                              beta_r, thr_r, back_beta, alpha,
                                              beta2, thr2);
    }
}